// Round 13
// baseline (61.692 us; speedup 1.0000x reference)
//
#include <hip/hip_runtime.h>

// Problem constants (B,V,T,H,W) = (32, 8, 2, 192, 288)
#define D        16        // V*T
#define NPAIR    136       // D*(D+1)/2 upper-triangle Gram entries
#define NVALS    152       // NPAIR + D row sums
#define HW       55296     // H*W
#define BSTRIDE  884736    // V*T*H*W (batch stride in floats)
#define NTOT     1769472   // B*H*W = N
#define CPB      6912      // columns per block (HW/CPB = 8 exact)
#define BPP      8         // blocks per batch-plane
#define G        256       // grid = NTOT / CPB == CU count: 1 block/CU, no tail
#define TCOLS    256       // columns per tile: one row = 1 KB = one gload_lds
#define TPB      27        // tiles per block (TPB * TCOLS == CPB)
#define NBUF     4         // LDS buffers -> prefetch depth 3 (counted vmcnt)
#define TSTR     260       // LDS row stride in floats (pad BETWEEN rows: each
                           // gload dest stays 1KB-contiguous)

typedef __attribute__((ext_vector_type(8))) short short8;
typedef __attribute__((ext_vector_type(4))) float f32x4;

__device__ __forceinline__ float wave_reduce(float x) {
    x += __shfl_down(x, 32);
    x += __shfl_down(x, 16);
    x += __shfl_down(x, 8);
    x += __shfl_down(x, 4);
    x += __shfl_down(x, 2);
    x += __shfl_down(x, 1);
    return x;
}

__host__ __device__ constexpr int tri_idx(int d, int e) {
    // d <= e required
    return d * D - (d * (d - 1)) / 2 + (e - d);
}

__device__ __forceinline__ short f2bf(float x) {
    // fp32 -> bf16 round-to-nearest-even on the bit pattern
    union { float f; unsigned u; } v; v.f = x;
    const unsigned r = (v.u + 0x7fffu + ((v.u >> 16) & 1u)) >> 16;
    return (short)r;
}

// r11 config (best measured: 45.5us total): 4 waves/block, counted-vmcnt
// depth-3 global_load_lds pipeline, G=256 = 1 block/CU (no scheduling tail).
// r12's 8-wave variant REGRESSED (61us): halving per-wave work didn't halve
// per-tile barrier/issue overhead; occupancy was never binding once the
// async pipeline existed. Kept here verbatim from r11.
// Buffer reuse race-free: stage(t+3) writes buf (t+3)&3 = (t-1)&3, whose
// last reader compute(t-1) finished before barrier(t).
__global__ __launch_bounds__(256)
void gram_mfma(const float* __restrict__ yt, const float* __restrict__ yp,
               float* __restrict__ part) {
    __shared__ __align__(16) float tile[NBUF][2][D][TSTR];   // 133,120 B

    const int tid  = threadIdx.x;
    const int lane = tid & 63;
    const int wid  = tid >> 6;
    const int b    = blockIdx.x / BPP;
    const int hw0  = (blockIdx.x - b * BPP) * CPB;
    const float* bt = yt + (size_t)b * BSTRIDE + hw0;
    const float* bp = yp + (size_t)b * BSTRIDE + hw0;

    const int row = lane & 15;         // MFMA row this lane feeds
    const int kg  = lane >> 4;         // k-slice group (0..3)

    f32x4 acc = {0.0f, 0.0f, 0.0f, 0.0f};
    float rs = 0.0f;

    // async stage of tile tt into buffer bb: 8 wave-instrs, 1 KB each
    auto stage = [&](int tt, int bb) {
#pragma unroll
        for (int s = 0; s < 4; ++s) {
            const int r = s * 4 + wid;
            const float* gt = bt + (size_t)r * HW + tt * TCOLS + lane * 4;
            const float* gq = bp + (size_t)r * HW + tt * TCOLS + lane * 4;
            __builtin_amdgcn_global_load_lds(
                (const __attribute__((address_space(1))) void*)gt,
                (__attribute__((address_space(3))) void*)&tile[bb][0][r][0],
                16, 0, 0);
            __builtin_amdgcn_global_load_lds(
                (const __attribute__((address_space(1))) void*)gq,
                (__attribute__((address_space(3))) void*)&tile[bb][1][r][0],
                16, 0, 0);
        }
    };

    auto compute = [&](int bb) {
#pragma unroll
        for (int c = 0; c < 2; ++c) {
            const int base = wid * 64 + c * 32 + kg * 8;
            const float* pt = &tile[bb][0][row][base];
            const float* pq = &tile[bb][1][row][base];
            const float r0 = pt[0] - pq[0], r1 = pt[1] - pq[1];
            const float r2 = pt[2] - pq[2], r3 = pt[3] - pq[3];
            const float r4 = pt[4] - pq[4], r5 = pt[5] - pq[5];
            const float r6 = pt[6] - pq[6], r7 = pt[7] - pq[7];
            rs += ((r0 + r1) + (r2 + r3)) + ((r4 + r5) + (r6 + r7));
            short8 f;
            f[0] = f2bf(r0); f[1] = f2bf(r1); f[2] = f2bf(r2); f[3] = f2bf(r3);
            f[4] = f2bf(r4); f[5] = f2bf(r5); f[6] = f2bf(r6); f[7] = f2bf(r7);
            acc = __builtin_amdgcn_mfma_f32_16x16x32_bf16(f, f, acc, 0, 0, 0);
        }
    };

    stage(0, 0);
    stage(1, 1);
    stage(2, 2);
    // main loop: 24 iterations (TPB-3), depth-3 steady state
#pragma unroll 4
    for (int t = 0; t < TPB - 3; ++t) {
        asm volatile("s_waitcnt vmcnt(16)" ::: "memory");   // tile t resident
        __builtin_amdgcn_s_barrier();
        stage(t + 3, (t + 3) & 3);
        compute(t & 3);
    }
    // epilogue: 3 tiles, no more staging
    asm volatile("s_waitcnt vmcnt(16)" ::: "memory");
    __builtin_amdgcn_s_barrier();
    compute((TPB - 3) & 3);
    asm volatile("s_waitcnt vmcnt(8)" ::: "memory");
    __builtin_amdgcn_s_barrier();
    compute((TPB - 2) & 3);
    asm volatile("s_waitcnt vmcnt(0)" ::: "memory");
    __builtin_amdgcn_s_barrier();
    compute((TPB - 1) & 3);

    // Row sum: combine the 4 k-slice lanes of each row (bits 4,5 of lane).
    rs += __shfl_xor(rs, 16);
    rs += __shfl_xor(rs, 32);

    // Block reduction: 4 waves' C tiles + row sums via LDS (epilogue only).
    __shared__ float cpart[4][D][D];
    __shared__ float spart[4][D];
    __syncthreads();   // all waves done with tile[] phase
    // C/D layout: col = lane&15, row = (lane>>4)*4 + i   [m89-verified]
#pragma unroll
    for (int i = 0; i < 4; ++i)
        cpart[wid][kg * 4 + i][row] = acc[i];
    if (lane < D) spart[wid][lane] = rs;
    __syncthreads();

    const int d = tid >> 4, e = tid & 15;
    if (d <= e) {
        const float s = (cpart[0][d][e] + cpart[1][d][e]) +
                        (cpart[2][d][e] + cpart[3][d][e]);
        part[tri_idx(d, e) * G + blockIdx.x] = s;
    }
    if (tid < D) {
        const float s = (spart[0][tid] + spart[1][tid]) +
                        (spart[2][tid] + spart[3][tid]);
        part[(NPAIR + tid) * G + blockIdx.x] = s;
    }
}

// Fused tail (single block, 256 threads): reduce G=256 partials per value,
// build cov, invert 16x16 via cooperative Gauss-Jordan, emit
// (1/N) * sum(P .* S).
__global__ void finalize_kernel(const float* __restrict__ part,
                                float* __restrict__ out) {
    __shared__ float Stri[NPAIR];
    __shared__ float Ssum[D];
    __shared__ float A[D][2 * D + 1];   // [cov | I], padded row

    const int tid  = threadIdx.x;
    const int lane = tid & 63;
    const int wv   = tid >> 6;

    // 1) Reduce G=256 block-partials per value: one wave per value row.
    for (int vi = wv; vi < NVALS; vi += 4) {
        float s = 0.0f;
#pragma unroll
        for (int j = 0; j < G / 64; ++j)
            s += part[vi * G + j * 64 + lane];
        s = wave_reduce(s);
        if (lane == 0) {
            if (vi < NPAIR) Stri[vi]         = s;
            else            Ssum[vi - NPAIR] = s;
        }
    }
    __syncthreads();

    // 2) Augmented matrix [cov | I]
    {
        const int d = tid >> 4, e = tid & 15;
        const int lo = d < e ? d : e, hi = d < e ? e : d;
        const float invN = 1.0f / (float)NTOT;
        const float cov = (Stri[tri_idx(lo, hi)] -
                           Ssum[d] * Ssum[e] * invN) /
                          (float)(NTOT - 1);
        A[d][e]     = cov;
        A[d][D + e] = (d == e) ? 1.0f : 0.0f;
    }
    __syncthreads();

    // 3) Gauss-Jordan (no pivoting; cov ~ 0.01*I, well-conditioned).
    const int r0 = tid >> 5;   // 0..7
    const int c0 = tid & 31;   // 0..31
    const int r1 = r0 + 8;
    for (int k = 0; k < D; ++k) {
        const float pivinv = 1.0f / A[k][k];
        __syncthreads();
        if (tid < 32) A[k][tid] *= pivinv;
        __syncthreads();
        const float f0 = A[r0][k];
        const float f1 = A[r1][k];
        __syncthreads();
        const float akc = A[k][c0];
        if (r0 != k) A[r0][c0] -= f0 * akc;
        if (r1 != k) A[r1][c0] -= f1 * akc;
        __syncthreads();
    }

    // 4) result = (1/N) * sum_{d,e} P[d][e] * S[d][e]
    float term;
    {
        const int d = tid >> 4, e = tid & 15;
        const int lo = d < e ? d : e, hi = d < e ? e : d;
        float p = A[d][D + e];
        const float scale = 1.0f;  // OFF_DIAGONAL_SCALE
        if (d != e) p *= scale;
        term = p * Stri[tri_idx(lo, hi)];
    }
    term = wave_reduce(term);

    __shared__ float wsum[4];
    if (lane == 0) wsum[wv] = term;
    __syncthreads();
    if (tid == 0) {
        const float tot = (wsum[0] + wsum[1]) + (wsum[2] + wsum[3]);
        out[0] = tot / (float)NTOT;
    }
}

extern "C" void kernel_launch(void* const* d_in, const int* in_sizes, int n_in,
                              void* d_out, int out_size, void* d_ws, size_t ws_size,
                              hipStream_t stream) {
    const float* y_true = (const float*)d_in[0];
    const float* y_pred = (const float*)d_in[1];
    float* out  = (float*)d_out;
    float* part = (float*)d_ws;   // needs NVALS * G * 4 = 155,648 bytes

    hipLaunchKernelGGL(gram_mfma, dim3(G), dim3(256), 0, stream,
                       y_true, y_pred, part);
    hipLaunchKernelGGL(finalize_kernel, dim3(1), dim3(256), 0, stream,
                       part, out);
}

// Round 14
// 45.354 us; speedup vs baseline: 1.3602x; 1.3602x over previous
//
#include <hip/hip_runtime.h>

// Problem constants (B,V,T,H,W) = (32, 8, 2, 192, 288)
#define D        16        // V*T
#define NPAIR    136       // D*(D+1)/2 upper-triangle Gram entries
#define NVALS    152       // NPAIR + D row sums
#define HW       55296     // H*W
#define BSTRIDE  884736    // V*T*H*W (batch stride in floats)
#define NTOT     1769472   // B*H*W = N
#define CPB      6912      // columns per block (HW/CPB = 8 exact)
#define BPP      8         // blocks per batch-plane
#define G        256       // grid = NTOT / CPB == CU count: 1 block/CU, no tail
#define TCOLS    256       // columns per tile: one row = 1 KB = one gload_lds
#define TPB      27        // tiles per block (TPB * TCOLS == CPB)
#define NBUF     4         // LDS buffers -> prefetch depth 3 (counted vmcnt)
#define TSTR     260       // LDS row stride in floats (pad BETWEEN rows: each
                           // gload dest stays 1KB-contiguous)

typedef __attribute__((ext_vector_type(8))) short short8;
typedef __attribute__((ext_vector_type(4))) float f32x4;

__device__ __forceinline__ float wave_reduce(float x) {
    x += __shfl_down(x, 32);
    x += __shfl_down(x, 16);
    x += __shfl_down(x, 8);
    x += __shfl_down(x, 4);
    x += __shfl_down(x, 2);
    x += __shfl_down(x, 1);
    return x;
}

__host__ __device__ constexpr int tri_idx(int d, int e) {
    // d <= e required
    return d * D - (d * (d - 1)) / 2 + (e - d);
}

__device__ __forceinline__ short f2bf(float x) {
    // fp32 -> bf16 round-to-nearest-even on the bit pattern
    union { float f; unsigned u; } v; v.f = x;
    const unsigned r = (v.u + 0x7fffu + ((v.u >> 16) & 1u)) >> 16;
    return (short)r;
}

// VERBATIM r11 (best measured: 45.5 us total). 4 waves/block, counted-vmcnt
// depth-3 global_load_lds pipeline, G=256 = 1 block/CU (no scheduling tail).
// r12 (8 thin waves) regressed to 61.0: per-tile barrier/issue overhead
// didn't halve; occupancy wasn't binding. r13 (fused single-block tail)
// regressed to 61.7: 38 serial wave-rounds of memory latency ~ +16 us vs
// the parallel 152-block reduce. Tail stays 3-kernel/parallel.
// Buffer reuse race-free: stage(t+3) writes buf (t+3)&3 = (t-1)&3, whose
// last reader compute(t-1) finished before barrier(t).
__global__ __launch_bounds__(256)
void gram_mfma(const float* __restrict__ yt, const float* __restrict__ yp,
               float* __restrict__ part) {
    __shared__ __align__(16) float tile[NBUF][2][D][TSTR];   // 133,120 B

    const int tid  = threadIdx.x;
    const int lane = tid & 63;
    const int wid  = tid >> 6;
    const int b    = blockIdx.x / BPP;
    const int hw0  = (blockIdx.x - b * BPP) * CPB;
    const float* bt = yt + (size_t)b * BSTRIDE + hw0;
    const float* bp = yp + (size_t)b * BSTRIDE + hw0;

    const int row = lane & 15;         // MFMA row this lane feeds
    const int kg  = lane >> 4;         // k-slice group (0..3)

    f32x4 acc = {0.0f, 0.0f, 0.0f, 0.0f};
    float rs = 0.0f;

    // async stage of tile tt into buffer bb: 8 wave-instrs, 1 KB each
    auto stage = [&](int tt, int bb) {
#pragma unroll
        for (int s = 0; s < 4; ++s) {
            const int r = s * 4 + wid;
            const float* gt = bt + (size_t)r * HW + tt * TCOLS + lane * 4;
            const float* gq = bp + (size_t)r * HW + tt * TCOLS + lane * 4;
            __builtin_amdgcn_global_load_lds(
                (const __attribute__((address_space(1))) void*)gt,
                (__attribute__((address_space(3))) void*)&tile[bb][0][r][0],
                16, 0, 0);
            __builtin_amdgcn_global_load_lds(
                (const __attribute__((address_space(1))) void*)gq,
                (__attribute__((address_space(3))) void*)&tile[bb][1][r][0],
                16, 0, 0);
        }
    };

    auto compute = [&](int bb) {
#pragma unroll
        for (int c = 0; c < 2; ++c) {
            const int base = wid * 64 + c * 32 + kg * 8;
            const float* pt = &tile[bb][0][row][base];
            const float* pq = &tile[bb][1][row][base];
            const float r0 = pt[0] - pq[0], r1 = pt[1] - pq[1];
            const float r2 = pt[2] - pq[2], r3 = pt[3] - pq[3];
            const float r4 = pt[4] - pq[4], r5 = pt[5] - pq[5];
            const float r6 = pt[6] - pq[6], r7 = pt[7] - pq[7];
            rs += ((r0 + r1) + (r2 + r3)) + ((r4 + r5) + (r6 + r7));
            short8 f;
            f[0] = f2bf(r0); f[1] = f2bf(r1); f[2] = f2bf(r2); f[3] = f2bf(r3);
            f[4] = f2bf(r4); f[5] = f2bf(r5); f[6] = f2bf(r6); f[7] = f2bf(r7);
            acc = __builtin_amdgcn_mfma_f32_16x16x32_bf16(f, f, acc, 0, 0, 0);
        }
    };

    stage(0, 0);
    stage(1, 1);
    stage(2, 2);
    // main loop: 24 iterations (TPB-3), depth-3 steady state
#pragma unroll 4
    for (int t = 0; t < TPB - 3; ++t) {
        asm volatile("s_waitcnt vmcnt(16)" ::: "memory");   // tile t resident
        __builtin_amdgcn_s_barrier();
        stage(t + 3, (t + 3) & 3);
        compute(t & 3);
    }
    // epilogue: 3 tiles, no more staging
    asm volatile("s_waitcnt vmcnt(16)" ::: "memory");
    __builtin_amdgcn_s_barrier();
    compute((TPB - 3) & 3);
    asm volatile("s_waitcnt vmcnt(8)" ::: "memory");
    __builtin_amdgcn_s_barrier();
    compute((TPB - 2) & 3);
    asm volatile("s_waitcnt vmcnt(0)" ::: "memory");
    __builtin_amdgcn_s_barrier();
    compute((TPB - 1) & 3);

    // Row sum: combine the 4 k-slice lanes of each row (bits 4,5 of lane).
    rs += __shfl_xor(rs, 16);
    rs += __shfl_xor(rs, 32);

    // Block reduction: 4 waves' C tiles + row sums via LDS (epilogue only).
    __shared__ float cpart[4][D][D];
    __shared__ float spart[4][D];
    __syncthreads();   // all waves done with tile[] phase
    // C/D layout: col = lane&15, row = (lane>>4)*4 + i   [m89-verified]
#pragma unroll
    for (int i = 0; i < 4; ++i)
        cpart[wid][kg * 4 + i][row] = acc[i];
    if (lane < D) spart[wid][lane] = rs;
    __syncthreads();

    const int d = tid >> 4, e = tid & 15;
    if (d <= e) {
        const float s = (cpart[0][d][e] + cpart[1][d][e]) +
                        (cpart[2][d][e] + cpart[3][d][e]);
        part[tri_idx(d, e) * G + blockIdx.x] = s;
    }
    if (tid < D) {
        const float s = (spart[0][tid] + spart[1][tid]) +
                        (spart[2][tid] + spart[3][tid]);
        part[(NPAIR + tid) * G + blockIdx.x] = s;
    }
}

// Stage A: one block per value; reduce G block-partials (coalesced, parallel).
__global__ void reduce_part(const float* __restrict__ part,
                            float* __restrict__ S) {
    const int vi   = blockIdx.x;
    const int tid  = threadIdx.x;
    const int lane = tid & 63;
    const int wv   = tid >> 6;
    float s = 0.0f;
    for (int j = tid; j < G; j += 256) s += part[vi * G + j];
    s = wave_reduce(s);
    __shared__ float ws[4];
    if (lane == 0) ws[wv] = s;
    __syncthreads();
    if (tid == 0) S[vi] = (ws[0] + ws[1]) + (ws[2] + ws[3]);
}

// Stage B (single block, 256 threads): build cov, invert 16x16 via
// cooperative Gauss-Jordan, emit (1/N) * sum(P .* S).
__global__ void finalize_kernel(const float* __restrict__ S,
                                float* __restrict__ out) {
    __shared__ float Stri[NPAIR];
    __shared__ float Ssum[D];
    __shared__ float A[D][2 * D + 1];   // [cov | I], padded row

    const int tid  = threadIdx.x;
    const int lane = tid & 63;
    const int wv   = tid >> 6;

    if (tid < NVALS) {
        const float v = S[tid];
        if (tid < NPAIR) Stri[tid]         = v;
        else             Ssum[tid - NPAIR] = v;
    }
    __syncthreads();

    // Augmented matrix [cov | I]
    {
        const int d = tid >> 4, e = tid & 15;
        const int lo = d < e ? d : e, hi = d < e ? e : d;
        const float invN = 1.0f / (float)NTOT;
        const float cov = (Stri[tri_idx(lo, hi)] -
                           Ssum[d] * Ssum[e] * invN) /
                          (float)(NTOT - 1);
        A[d][e]     = cov;
        A[d][D + e] = (d == e) ? 1.0f : 0.0f;
    }
    __syncthreads();

    // Gauss-Jordan (no pivoting; cov ~ 0.01*I, well-conditioned).
    const int r0 = tid >> 5;   // 0..7
    const int c0 = tid & 31;   // 0..31
    const int r1 = r0 + 8;
    for (int k = 0; k < D; ++k) {
        const float pivinv = 1.0f / A[k][k];
        __syncthreads();
        if (tid < 32) A[k][tid] *= pivinv;
        __syncthreads();
        const float f0 = A[r0][k];
        const float f1 = A[r1][k];
        __syncthreads();
        const float akc = A[k][c0];
        if (r0 != k) A[r0][c0] -= f0 * akc;
        if (r1 != k) A[r1][c0] -= f1 * akc;
        __syncthreads();
    }

    // result = (1/N) * sum_{d,e} P[d][e] * S[d][e]
    float term;
    {
        const int d = tid >> 4, e = tid & 15;
        const int lo = d < e ? d : e, hi = d < e ? e : d;
        float p = A[d][D + e];
        const float scale = 1.0f;  // OFF_DIAGONAL_SCALE
        if (d != e) p *= scale;
        term = p * Stri[tri_idx(lo, hi)];
    }
    term = wave_reduce(term);

    __shared__ float wsum[4];
    if (lane == 0) wsum[wv] = term;
    __syncthreads();
    if (tid == 0) {
        const float tot = (wsum[0] + wsum[1]) + (wsum[2] + wsum[3]);
        out[0] = tot / (float)NTOT;
    }
}

extern "C" void kernel_launch(void* const* d_in, const int* in_sizes, int n_in,
                              void* d_out, int out_size, void* d_ws, size_t ws_size,
                              hipStream_t stream) {
    const float* y_true = (const float*)d_in[0];
    const float* y_pred = (const float*)d_in[1];
    float* out  = (float*)d_out;
    float* part = (float*)d_ws;                 // NVALS * G * 4 = 155,648 B
    float* S    = part + (size_t)NVALS * G;     // + NVALS * 4 B

    hipLaunchKernelGGL(gram_mfma, dim3(G), dim3(256), 0, stream,
                       y_true, y_pred, part);
    hipLaunchKernelGGL(reduce_part, dim3(NVALS), dim3(256), 0, stream,
                       part, S);
    hipLaunchKernelGGL(finalize_kernel, dim3(1), dim3(256), 0, stream,
                       S, out);
}